// Round 12
// baseline (380.046 us; speedup 1.0000x reference)
//
#include <hip/hip_runtime.h>
#include <stdint.h>
#include <string.h>

typedef unsigned short u16;
typedef __attribute__((ext_vector_type(8))) short short8_t;   // 8 x bf16 (4 VGPRs)
typedef __attribute__((ext_vector_type(4))) float f32x4;

typedef const __attribute__((address_space(1))) void GV;
typedef __attribute__((address_space(3))) void LV;

__device__ __forceinline__ void gload_lds16(const void* g, void* l) {
  // async global->LDS, 16B per lane; LDS dest is wave-uniform base + lane*16
  __builtin_amdgcn_global_load_lds((GV*)g, (LV*)l, 16, 0, 0);
}

__device__ __forceinline__ u16 f2bf(float f) {
  union { float f; uint32_t u; } v; v.f = f;
  return (u16)((v.u + 0x7FFFu + ((v.u >> 16) & 1u)) >> 16);  // RNE
}

__device__ __forceinline__ f32x4 fz4() { f32x4 v = {0.f, 0.f, 0.f, 0.f}; return v; }

// ---------------- casts fp32 -> bf16 (4 elems/thread), merged launches ----------------
__global__ __launch_bounds__(256) void cast2_kernel(const float* __restrict__ in0,
                                                    const float* __restrict__ in1,
                                                    u16* __restrict__ out0,
                                                    u16* __restrict__ out1) {
  const int half = blockIdx.x >> 14;                 // 16384 blocks per input
  const float* in = half ? in1 : in0;
  u16* out = half ? out1 : out0;
  int i = ((blockIdx.x & 16383) * 256 + threadIdx.x) * 4;
  float4 v = *(const float4*)(in + i);
  ushort4 o;
  o.x = f2bf(v.x); o.y = f2bf(v.y); o.z = f2bf(v.z); o.w = f2bf(v.w);
  *(ushort4*)(out + i) = o;
}

__global__ __launch_bounds__(256) void cast4_kernel(const float* __restrict__ w0,
                                                    const float* __restrict__ w1,
                                                    const float* __restrict__ w2,
                                                    const float* __restrict__ w3,
                                                    u16* __restrict__ o0,
                                                    u16* __restrict__ o1,
                                                    u16* __restrict__ o2,
                                                    u16* __restrict__ o3) {
  const int sel = blockIdx.x >> 10;                  // 1024 blocks per weight
  const float* in = sel == 0 ? w0 : sel == 1 ? w1 : sel == 2 ? w2 : w3;
  u16* out = sel == 0 ? o0 : sel == 1 ? o1 : sel == 2 ? o2 : o3;
  int i = ((blockIdx.x & 1023) * 256 + threadIdx.x) * 4;
  float4 v = *(const float4*)(in + i);
  ushort4 o;
  o.x = f2bf(v.x); o.y = f2bf(v.y); o.z = f2bf(v.z); o.w = f2bf(v.w);
  *(ushort4*)(out + i) = o;
}

// ======== 256x256 8-phase GEMM core (T2+T3+T4+T5): C = A[M,K]*B[N,K]^T + bias ========
// Schedule unchanged from R6 (measured good, absmax stable). R11 T1 mapping: xcd=bid&7,
// n fastest, contiguous 8-m-tile range per XCD (A 4MB + B 2MB ~ L2-resident).
// mode (runtime, epilogue-only uniform branch): 0 = f32 linear, 1 = bf16 linear,
// 2 = bf16 scattered to VT layout [hb][d][t] (fuses the V transpose; store count
// identical to linear — epilogue was already scalar 2B stores).
// M=16384, N=K=1024 fixed.
__device__ __forceinline__ void gemm8_core(int bid, const u16* __restrict__ A,
                                           const u16* __restrict__ B,
                                           const float* __restrict__ bias,
                                           void* __restrict__ Cout, int mode,
                                           u16* Al, u16* Bl) {
  const int M = 16384, N = 1024, K = 1024;
  (void)M;
  const int tid = threadIdx.x, w = tid >> 6, l = tid & 63;
  const int g = l >> 4, q = l & 15;
  const int xcd = bid & 7;
  const int nt = (bid >> 3) & 3;                 // n fastest within XCD
  const int mt = xcd * 8 + (bid >> 5);           // contiguous m-range per XCD
  const int n0 = nt * 256, m0 = mt * 256;
  const int NT = K >> 6;
  const int ah = w >> 2;            // this wave's A half
  const int bh = (w & 3) >> 1;      // this wave's B half
  const int brow0 = ((w & 3) & 1) * 64;

#define STAGE_A(S, half)                                                          \
  {                                                                               \
    _Pragma("unroll") for (int j_ = 0; j_ < 2; ++j_) {                            \
      const int idx_ = j_ * 512 + tid;                                            \
      const int row_ = idx_ >> 3;                                                 \
      const int sl_ = (idx_ & 7) ^ (((idx_ >> 5) & 1) << 1);                      \
      gload_lds16(A + (size_t)(m0 + (half) * 128 + row_) * K + (S) * 64 + sl_ * 8,\
                  Al + ((S) & 1) * 16384 + (half) * 8192 + (j_ * 512 + w * 64) * 8);\
    }                                                                             \
  }
#define STAGE_B(S, half)                                                          \
  {                                                                               \
    _Pragma("unroll") for (int j_ = 0; j_ < 2; ++j_) {                            \
      const int idx_ = j_ * 512 + tid;                                            \
      const int row_ = idx_ >> 3;                                                 \
      const int sl_ = (idx_ & 7) ^ (((idx_ >> 5) & 1) << 1);                      \
      gload_lds16(B + (size_t)(n0 + (half) * 128 + row_) * K + (S) * 64 + sl_ * 8,\
                  Bl + ((S) & 1) * 16384 + (half) * 8192 + (j_ * 512 + w * 64) * 8);\
    }                                                                             \
  }

  f32x4 acc[8][4];
#pragma unroll
  for (int i = 0; i < 8; ++i)
#pragma unroll
    for (int n = 0; n < 4; ++n) acc[i][n] = fz4();

  // bias per lane (epilogue operand), load early
  float bv[4];
#pragma unroll
  for (int nf = 0; nf < 4; ++nf) bv[nf] = bias[n0 + (w & 3) * 64 + nf * 16 + q];

  // prologue: stage tiles 0 and 1 fully (16 loads/thread)
  STAGE_A(0, 0); STAGE_A(0, 1); STAGE_B(0, 0); STAGE_B(0, 1);
  STAGE_A(1, 0); STAGE_A(1, 1); STAGE_B(1, 0); STAGE_B(1, 1);
  asm volatile("s_waitcnt vmcnt(8)");          // tile 0 landed; tile 1 in flight
  __builtin_amdgcn_s_barrier();

  short8_t bfr[4][2];
  for (int S = 0; S < NT; ++S) {
    const int bs = (S & 1) * 16384;
#pragma unroll
    for (int p = 0; p < 4; ++p) {
      // ---- ds_read register subtiles ----
      short8_t afr[2][2];
#pragma unroll
      for (int mi = 0; mi < 2; ++mi)
#pragma unroll
        for (int kk = 0; kk < 2; ++kk) {
          const int r = (2 * p + mi) * 16 + q;
          afr[mi][kk] = *(const short8_t*)(Al + bs + ah * 8192 + r * 64 +
                                           ((kk * 4 + g) ^ (((r >> 2) & 1) << 1)) * 8);
        }
      if (p == 0) {
#pragma unroll
        for (int nf = 0; nf < 4; ++nf)
#pragma unroll
          for (int kk = 0; kk < 2; ++kk) {
            const int r = brow0 + nf * 16 + q;
            bfr[nf][kk] = *(const short8_t*)(Bl + bs + bh * 8192 + r * 64 +
                                             ((kk * 4 + g) ^ (((r >> 2) & 1) << 1)) * 8);
          }
      }
      // ---- issue one half-tile stage ----
      if (p == 0 && S >= 1 && S + 1 < NT) STAGE_A(S + 1, 0);
      if (p == 1 && S >= 1 && S + 1 < NT) STAGE_A(S + 1, 1);
      if (p == 2 && S + 2 < NT) STAGE_B(S + 2, 0);
      if (p == 3 && S + 2 < NT) STAGE_B(S + 2, 1);
      // ---- counted vmcnt once per K-tile, fencing tile S+1's reads ----
      if (p == 3) {
        if (S == NT - 2) { asm volatile("s_waitcnt vmcnt(0)"); }
        else if (S < NT - 2) { asm volatile("s_waitcnt vmcnt(4)"); }
      }
      __builtin_amdgcn_s_barrier();
      asm volatile("s_waitcnt lgkmcnt(0)" ::: "memory");
      __builtin_amdgcn_sched_barrier(0);
      __builtin_amdgcn_s_setprio(1);
#pragma unroll
      for (int nf = 0; nf < 4; ++nf)
#pragma unroll
        for (int mi = 0; mi < 2; ++mi)
#pragma unroll
          for (int kk = 0; kk < 2; ++kk)
            acc[2 * p + mi][nf] = __builtin_amdgcn_mfma_f32_16x16x32_bf16(
                afr[mi][kk], bfr[nf][kk], acc[2 * p + mi][nf], 0, 0, 0);
      __builtin_amdgcn_s_setprio(0);
      __builtin_amdgcn_s_barrier();
    }
  }
#undef STAGE_A
#undef STAGE_B

  // epilogue: bias + store (C/D: col=lane&15, row=(lane>>4)*4+j)
  const int wr = (w >> 2) * 128, wc = (w & 3) * 64;
#pragma unroll
  for (int nf = 0; nf < 4; ++nf) {
    const int col = n0 + wc + nf * 16 + q;
#pragma unroll
    for (int mf = 0; mf < 8; ++mf) {
      const int rowb = m0 + wr + mf * 16 + g * 4;
#pragma unroll
      for (int j = 0; j < 4; ++j) {
        const float vv = acc[mf][nf][j] + bv[nf];
        const int row = rowb + j;
        if (mode == 0) {
          ((float*)Cout)[(size_t)row * N + col] = vv;
        } else if (mode == 1) {
          ((u16*)Cout)[(size_t)row * N + col] = f2bf(vv);
        } else {
          // VT layout [hb][d][t]: hb=row>>8, d=col&255, t=(row&255)*4+(col>>8)
          ((u16*)Cout)[((size_t)(row >> 8) << 18) + ((size_t)(col & 255) << 10) +
                       ((row & 255) * 4) + (col >> 8)] = f2bf(vv);
        }
      }
    }
  }
}

// Merged Q/K/V GEMMs: 768 blocks, chunk of 256 per GEMM (256 % 8 == 0 preserves the
// per-chunk XCD mapping). Removes 2 kernel-boundary bubbles; V writes VT directly.
__global__ __launch_bounds__(512, 2) void gemm8_qkv(const u16* __restrict__ Xb,
                                                    const u16* __restrict__ Yb,
                                                    const u16* __restrict__ Wqb,
                                                    const u16* __restrict__ Wkb,
                                                    const u16* __restrict__ Wvb,
                                                    const float* __restrict__ bq,
                                                    const float* __restrict__ bk,
                                                    const float* __restrict__ bv,
                                                    u16* __restrict__ Qb,
                                                    u16* __restrict__ Kb,
                                                    u16* __restrict__ VTb) {
  __shared__ u16 Al[2 * 16384];
  __shared__ u16 Bl[2 * 16384];
  const int sel = blockIdx.x >> 8, bid = blockIdx.x & 255;
  const u16* A;
  const u16* B;
  const float* bias;
  void* C;
  int mode;
  if (sel == 0)      { A = Xb; B = Wqb; bias = bq; C = Qb;  mode = 1; }
  else if (sel == 1) { A = Yb; B = Wkb; bias = bk; C = Kb;  mode = 1; }
  else               { A = Yb; B = Wvb; bias = bv; C = VTb; mode = 2; }
  gemm8_core(bid, A, B, bias, C, mode, Al, Bl);
}

__global__ __launch_bounds__(512, 2) void gemm8_out(const u16* __restrict__ A,
                                                    const u16* __restrict__ B,
                                                    const float* __restrict__ bias,
                                                    float* __restrict__ C) {
  __shared__ u16 Al[2 * 16384];
  __shared__ u16 Bl[2 * 16384];
  gemm8_core(blockIdx.x, A, B, bias, C, 0, Al, Bl);
}

// -------- fused attention: R8 structure (KVBLK=32, T14 reg-staged) + T12 P-repack ----
// (unchanged from R10 — 142us plateau; five structural levers exhausted)
__global__ __launch_bounds__(256) void attn_kernel(const u16* __restrict__ Q,
                                                   const u16* __restrict__ Kf,
                                                   const u16* __restrict__ VT,
                                                   const float* __restrict__ adj,
                                                   u16* __restrict__ O) {
  __shared__ u16 Ks[32 * 256];    // K tile [key][d], 512B rows, slot ^= (row&7)
  __shared__ u16 Vs[256 * 32];    // V^T tile [d][key], 64B rows, sl ^= ((dr>>1)&3)
  const int tid = threadIdx.x, w = tid >> 6, l = tid & 63;
  const int g = l >> 4, q = l & 15;
  const int bid = blockIdx.x;
  const int xcd = bid & 7, idx = bid >> 3;           // 8 XCDs x 128 blocks
  const int b = xcd * 2 + (idx >> 6);                // 2 batches per XCD
  const int qb = (idx >> 2) & 15, h = idx & 3;       // qb sweeps, h fastest
  const int hb = h * 16 + b;
  const int q0 = qb * 64;
  const u16* qb_p = Q + ((size_t)hb * 1024 + q0 + w * 16) * 256;
  const u16* kb = Kf + (size_t)hb * 1024 * 256;
  const u16* vtb = VT + (size_t)hb * 256 * 1024;
  const float* adjr = adj + (size_t)b * 1024 * 1024 + (size_t)(q0 + w * 16 + q) * 1024;

  // per-thread staging geometry (constant across iterations)
  const int krow_b = tid >> 5;         // + i*8 -> K row 0..31
  const int kslot = tid & 31;          // 16B slot within 512B K row
  const int vdr_b = tid >> 2;          // + i*64 -> V^T d-row 0..255
  const int vsl = tid & 3;             // 16B slot within 64B V row

  // Q fragments (B-operand of S^T): lane q=l&15, d = kk*32 + g*8 + j
  short8_t qf[8];
#pragma unroll
  for (int kk = 0; kk < 8; ++kk)
    qf[kk] = *(const short8_t*)(qb_p + (size_t)q * 256 + kk * 32 + g * 8);

  f32x4 o[16];  // O^T accum: lane holds O[q][d], d = n*16 + g*4 + r
#pragma unroll
  for (int n = 0; n < 16; ++n) o[n] = fz4();
  float mrun = -1e30f, lrun = 0.f;

  short8_t kst[4], vst[4];   // reg-staged next tile (+32 VGPR)

#define LOADREGS(ktt)                                                              \
  {                                                                                \
    _Pragma("unroll") for (int i_ = 0; i_ < 4; ++i_) {                             \
      const int row_ = i_ * 8 + krow_b;                                            \
      kst[i_] = *(const short8_t*)(kb + (size_t)((ktt) * 32 + row_) * 256 +        \
                                   kslot * 8);                                     \
    }                                                                              \
    _Pragma("unroll") for (int i_ = 0; i_ < 4; ++i_) {                             \
      const int dr_ = i_ * 64 + vdr_b;                                             \
      vst[i_] = *(const short8_t*)(vtb + (size_t)dr_ * 1024 + (ktt) * 32 +         \
                                   vsl * 8);                                       \
    }                                                                              \
  }
#define WRITEREGS()                                                                \
  {                                                                                \
    _Pragma("unroll") for (int i_ = 0; i_ < 4; ++i_) {                             \
      const int row_ = i_ * 8 + krow_b;                                            \
      *(short8_t*)((char*)Ks + row_ * 512 + ((kslot ^ (row_ & 7)) * 16)) = kst[i_];\
    }                                                                              \
    _Pragma("unroll") for (int i_ = 0; i_ < 4; ++i_) {                             \
      const int dr_ = i_ * 64 + vdr_b;                                             \
      *(short8_t*)((char*)Vs + dr_ * 64 + ((vsl ^ ((dr_ >> 1) & 3)) * 16)) = vst[i_];\
    }                                                                              \
  }

  // prologue: tile 0 regs -> LDS; adj tile 0 prefetch
  LOADREGS(0);
  float4 a0 = *(const float4*)(adjr + 0 * 32 + 0 * 16 + g * 4);
  float4 a1 = *(const float4*)(adjr + 0 * 32 + 1 * 16 + g * 4);
  WRITEREGS();
  __syncthreads();

  for (int kt = 0; kt < 32; ++kt) {
    float4 n0v = a0, n1v = a1;
    if (kt < 31) {
      LOADREGS(kt + 1);            // issue early: latency hides under QK+sm+PV
      n0v = *(const float4*)(adjr + (kt + 1) * 32 + 0 * 16 + g * 4);
      n1v = *(const float4*)(adjr + (kt + 1) * 32 + 1 * 16 + g * 4);
    }

    // S^T = K Q^T : 2 key-frags x 8 d-steps. lane: q=l&15, k = f*16 + g*4 + r
    f32x4 s[2];
    __builtin_amdgcn_s_setprio(1);
#pragma unroll
    for (int f = 0; f < 2; ++f) {
      f32x4 a = fz4();
      const int row = f * 16 + q;
      const char* kr = (const char*)Ks + row * 512;
#pragma unroll
      for (int kk = 0; kk < 8; ++kk) {
        const int cb = kk * 64 + g * 16;
        short8_t kfr = *(const short8_t*)(kr + (cb ^ ((row & 7) << 4)));
        a = __builtin_amdgcn_mfma_f32_16x16x32_bf16(kfr, qf[kk], a, 0, 0, 0);
      }
      s[f] = a;
    }
    __builtin_amdgcn_s_setprio(0);

    // scale + adj (vectorized float4 per frag)
#pragma unroll
    for (int j = 0; j < 4; ++j) {
      s[0][j] = s[0][j] * 0.03125f + ((const float*)&a0)[j];
      s[1][j] = s[1][j] * 0.03125f + ((const float*)&a1)[j];
    }

    // per-lane online softmax: 8 local values + reduce across g (xor 16,32)
    float pmax = s[0][0];
#pragma unroll
    for (int j = 1; j < 4; ++j) pmax = fmaxf(pmax, s[0][j]);
#pragma unroll
    for (int j = 0; j < 4; ++j) pmax = fmaxf(pmax, s[1][j]);
    pmax = fmaxf(pmax, __shfl_xor(pmax, 16));
    pmax = fmaxf(pmax, __shfl_xor(pmax, 32));

    if (!__all(pmax - mrun <= 8.0f)) {          // T13 defer-max
      const float mn = fmaxf(mrun, pmax);
      const float al = __expf(mrun - mn);
      mrun = mn;
      lrun *= al;
#pragma unroll
      for (int n = 0; n < 16; ++n)
#pragma unroll
        for (int r = 0; r < 4; ++r) o[n][r] *= al;
    }

    float sum = 0.f;
#pragma unroll
    for (int f = 0; f < 2; ++f)
#pragma unroll
      for (int j = 0; j < 4; ++j) {
        const float p = __expf(s[f][j] - mrun);
        s[f][j] = p;
        sum += p;
      }
    sum += __shfl_xor(sum, 16);
    sum += __shfl_xor(sum, 32);
    lrun += sum;

    // ---- T12: P^T -> MFMA B-operand fully in-register ----
    uint32_t W00, W01, W10, W11;
    asm("v_cvt_pk_bf16_f32 %0, %1, %2" : "=v"(W00) : "v"(s[0][0]), "v"(s[0][1]));
    asm("v_cvt_pk_bf16_f32 %0, %1, %2" : "=v"(W01) : "v"(s[0][2]), "v"(s[0][3]));
    asm("v_cvt_pk_bf16_f32 %0, %1, %2" : "=v"(W10) : "v"(s[1][0]), "v"(s[1][1]));
    asm("v_cvt_pk_bf16_f32 %0, %1, %2" : "=v"(W11) : "v"(s[1][2]), "v"(s[1][3]));
    const uint32_t sA0 = (g < 2) ? W00 : W10;   // W[g>>1][0]
    const uint32_t sA1 = (g < 2) ? W01 : W11;   // W[g>>1][1]
    const uint32_t sB0 = (g < 2) ? W10 : W00;   // W[(g>>1)^1][0]
    const uint32_t sB1 = (g < 2) ? W11 : W01;   // W[(g>>1)^1][1]
    const uint32_t A0 = (uint32_t)__shfl_xor((int)sA0, 16);
    const uint32_t A1 = (uint32_t)__shfl_xor((int)sA1, 16);
    const uint32_t B0 = (uint32_t)__shfl_xor((int)sB0, 32);
    const uint32_t B1 = (uint32_t)__shfl_xor((int)sB1, 32);
    const uint32_t C0 = (uint32_t)__shfl_xor((int)sB0, 48);
    const uint32_t C1 = (uint32_t)__shfl_xor((int)sB1, 48);
    union { uint32_t u[4]; short8_t v; } pu;
    pu.u[0] = (g == 0) ? W00 : (g == 1) ? C0 : (g == 2) ? B0 : A0;
    pu.u[1] = (g == 0) ? W01 : (g == 1) ? C1 : (g == 2) ? B1 : A1;
    pu.u[2] = (g == 0) ? A0 : (g == 1) ? B0 : (g == 2) ? C0 : W10;
    pu.u[3] = (g == 0) ? A1 : (g == 1) ? B1 : (g == 2) ? C1 : W11;
    const short8_t pa = pu.v;

    // O^T += V^T P^T : 16 d-frags, one k-step (K=32 keys)
    __builtin_amdgcn_s_setprio(1);
#pragma unroll
    for (int n = 0; n < 16; ++n) {
      const int dr = n * 16 + q;
      const int sl = g ^ ((dr >> 1) & 3);
      short8_t vf = *(const short8_t*)((const char*)Vs + dr * 64 + sl * 16);
      o[n] = __builtin_amdgcn_mfma_f32_16x16x32_bf16(vf, pa, o[n], 0, 0, 0);
    }
    __builtin_amdgcn_s_setprio(0);

    if (kt < 31) {
      __syncthreads();             // all waves done reading Ks/Vs
      WRITEREGS();                 // compiler inserts vmcnt for reg deps
      __syncthreads();             // writes visible
    }
    a0 = n0v; a1 = n1v;
  }
#undef LOADREGS
#undef WRITEREGS

  // epilogue: normalize, packed 8B stores; lane owns row q, d = n*16+g*4+r
  const float inv = 1.0f / lrun;
  u16* ob = O + ((size_t)hb * 1024 + q0 + w * 16 + q) * 256;
#pragma unroll
  for (int n = 0; n < 16; ++n) {
    ushort4 st;
    st.x = f2bf(o[n][0] * inv); st.y = f2bf(o[n][1] * inv);
    st.z = f2bf(o[n][2] * inv); st.w = f2bf(o[n][3] * inv);
    *(ushort4*)(ob + n * 16 + g * 4) = st;
  }
}

extern "C" void kernel_launch(void* const* d_in, const int* in_sizes, int n_in,
                              void* d_out, int out_size, void* d_ws, size_t ws_size,
                              hipStream_t stream) {
  (void)in_sizes; (void)n_in; (void)out_size; (void)ws_size;
  const float* x   = (const float*)d_in[0];
  const float* y   = (const float*)d_in[1];
  const float* adj = (const float*)d_in[2];
  const float* Wq  = (const float*)d_in[3];
  const float* bq  = (const float*)d_in[4];
  const float* Wk  = (const float*)d_in[5];
  const float* bk  = (const float*)d_in[6];
  const float* Wv  = (const float*)d_in[7];
  const float* bv  = (const float*)d_in[8];
  const float* Wo  = (const float*)d_in[9];
  const float* bo  = (const float*)d_in[10];

  char* ws = (char*)d_ws;
  const size_t MB = 1ull << 20;
  u16* Xb  = (u16*)(ws + 0);        // 32MB, reused as Tmp after Q GEMM
  u16* Yb  = (u16*)(ws + 32 * MB);  // 32MB
  u16* Wqb = (u16*)(ws + 64 * MB);  // 2MB each
  u16* Wkb = (u16*)(ws + 66 * MB);
  u16* Wvb = (u16*)(ws + 68 * MB);
  u16* Wob = (u16*)(ws + 70 * MB);
  u16* Qb  = (u16*)(ws + 72 * MB);  // 32MB
  u16* Kb  = (u16*)(ws + 104 * MB);
  u16* VTb = (u16*)(ws + 168 * MB); // V GEMM writes transposed layout directly
  u16* Tmp = Xb;

  cast2_kernel<<<32768, 256, 0, stream>>>(x, y, Xb, Yb);
  cast4_kernel<<<4096, 256, 0, stream>>>(Wq, Wk, Wv, Wo, Wqb, Wkb, Wvb, Wob);

  gemm8_qkv<<<768, 512, 0, stream>>>(Xb, Yb, Wqb, Wkb, Wvb, bq, bk, bv, Qb, Kb, VTb);

  attn_kernel<<<1024, 256, 0, stream>>>(Qb, Kb, VTb, adj, Tmp);

  gemm8_out<<<256, 512, 0, stream>>>(Tmp, Wob, bo, (float*)d_out);
}

// Round 13
// 360.051 us; speedup vs baseline: 1.0555x; 1.0555x over previous
//
#include <hip/hip_runtime.h>
#include <stdint.h>
#include <string.h>

typedef unsigned short u16;
typedef __attribute__((ext_vector_type(8))) short short8_t;   // 8 x bf16 (4 VGPRs)
typedef __attribute__((ext_vector_type(4))) float f32x4;

typedef const __attribute__((address_space(1))) void GV;
typedef __attribute__((address_space(3))) void LV;

__device__ __forceinline__ void gload_lds16(const void* g, void* l) {
  // async global->LDS, 16B per lane; LDS dest is wave-uniform base + lane*16
  __builtin_amdgcn_global_load_lds((GV*)g, (LV*)l, 16, 0, 0);
}

__device__ __forceinline__ u16 f2bf(float f) {
  union { float f; uint32_t u; } v; v.f = f;
  return (u16)((v.u + 0x7FFFu + ((v.u >> 16) & 1u)) >> 16);  // RNE
}

__device__ __forceinline__ f32x4 fz4() { f32x4 v = {0.f, 0.f, 0.f, 0.f}; return v; }

// ---------------- casts fp32 -> bf16 (4 elems/thread), merged launches ----------------
__global__ __launch_bounds__(256) void cast2_kernel(const float* __restrict__ in0,
                                                    const float* __restrict__ in1,
                                                    u16* __restrict__ out0,
                                                    u16* __restrict__ out1) {
  const int half = blockIdx.x >> 14;                 // 16384 blocks per input
  const float* in = half ? in1 : in0;
  u16* out = half ? out1 : out0;
  int i = ((blockIdx.x & 16383) * 256 + threadIdx.x) * 4;
  float4 v = *(const float4*)(in + i);
  ushort4 o;
  o.x = f2bf(v.x); o.y = f2bf(v.y); o.z = f2bf(v.z); o.w = f2bf(v.w);
  *(ushort4*)(out + i) = o;
}

__global__ __launch_bounds__(256) void cast4_kernel(const float* __restrict__ w0,
                                                    const float* __restrict__ w1,
                                                    const float* __restrict__ w2,
                                                    const float* __restrict__ w3,
                                                    u16* __restrict__ o0,
                                                    u16* __restrict__ o1,
                                                    u16* __restrict__ o2,
                                                    u16* __restrict__ o3) {
  const int sel = blockIdx.x >> 10;                  // 1024 blocks per weight
  const float* in = sel == 0 ? w0 : sel == 1 ? w1 : sel == 2 ? w2 : w3;
  u16* out = sel == 0 ? o0 : sel == 1 ? o1 : sel == 2 ? o2 : o3;
  int i = ((blockIdx.x & 1023) * 256 + threadIdx.x) * 4;
  float4 v = *(const float4*)(in + i);
  ushort4 o;
  o.x = f2bf(v.x); o.y = f2bf(v.y); o.z = f2bf(v.z); o.w = f2bf(v.w);
  *(ushort4*)(out + i) = o;
}

// ======== 256x256 8-phase GEMM (T2+T3+T4+T5): C = A[M,K]*B[N,K]^T + bias ========
// Schedule unchanged from R6. R11 T1 mapping: xcd=bid&7, n fastest, contiguous
// 8-m-tile range per XCD (A 4MB + B 2MB ~ L2-resident). Separate launches (R12's
// merge regressed: write amplification + lost attribution).
// MODE 0 = f32 linear (out GEMM), 1 = bf16 linear (Q,K), 2 = bf16 -> VT[hb][d][t]
// with COLUMN-REMAPPED n-tile: logical u in [0,256) -> physical col
// (u>>6)*256 + nt*64 + (u&63). Then d = nt*64+nf*16+q, t = (row&255)*4 + (wc>>6):
// one block covers ALL t mod-4 classes and full t-range for 64 d-rows -> VT rows
// written contiguously, no stride-4 write amplification (R12's failure: WRITE 184MB).
template <int MODE>
__global__ __launch_bounds__(512, 2) void gemm8(const u16* __restrict__ A,
                                                const u16* __restrict__ B,
                                                const float* __restrict__ bias,
                                                void* __restrict__ Cout,
                                                int M, int N, int K) {
  __shared__ u16 Al[2 * 16384];   // [buf][half 128 rows][64 k] swizzled
  __shared__ u16 Bl[2 * 16384];
  const int tid = threadIdx.x, w = tid >> 6, l = tid & 63;
  const int g = l >> 4, q = l & 15;
  const int bid = blockIdx.x;
  const int xcd = bid & 7;
  const int nt = (bid >> 3) & 3;                 // n fastest within XCD
  const int mt = xcd * 8 + (bid >> 5);           // contiguous m-range per XCD
  const int n0 = nt * 256, m0 = mt * 256;
  const int NT = K >> 6;
  const int ah = w >> 2;            // this wave's A half
  const int bh = (w & 3) >> 1;      // this wave's B half
  const int brow0 = ((w & 3) & 1) * 64;

  // logical B row u -> physical B row (column of C)
#define BROW(u) (MODE == 2 ? ((((u) >> 6) << 8) + nt * 64 + ((u) & 63)) : (n0 + (u)))

#define STAGE_A(S, half)                                                          \
  {                                                                               \
    _Pragma("unroll") for (int j_ = 0; j_ < 2; ++j_) {                            \
      const int idx_ = j_ * 512 + tid;                                            \
      const int row_ = idx_ >> 3;                                                 \
      const int sl_ = (idx_ & 7) ^ (((idx_ >> 5) & 1) << 1);                      \
      gload_lds16(A + (size_t)(m0 + (half) * 128 + row_) * K + (S) * 64 + sl_ * 8,\
                  Al + ((S) & 1) * 16384 + (half) * 8192 + (j_ * 512 + w * 64) * 8);\
    }                                                                             \
  }
#define STAGE_B(S, half)                                                          \
  {                                                                               \
    _Pragma("unroll") for (int j_ = 0; j_ < 2; ++j_) {                            \
      const int idx_ = j_ * 512 + tid;                                            \
      const int row_ = idx_ >> 3;                                                 \
      const int sl_ = (idx_ & 7) ^ (((idx_ >> 5) & 1) << 1);                      \
      const int pr_ = BROW((half) * 128 + row_);                                  \
      gload_lds16(B + (size_t)pr_ * K + (S) * 64 + sl_ * 8,                       \
                  Bl + ((S) & 1) * 16384 + (half) * 8192 + (j_ * 512 + w * 64) * 8);\
    }                                                                             \
  }

  f32x4 acc[8][4];
#pragma unroll
  for (int i = 0; i < 8; ++i)
#pragma unroll
    for (int n = 0; n < 4; ++n) acc[i][n] = fz4();

  // bias per lane (epilogue operand), load early; index = physical column
  const int wc = (w & 3) * 64;
  float bv[4];
#pragma unroll
  for (int nf = 0; nf < 4; ++nf) bv[nf] = bias[BROW(wc + nf * 16 + q)];

  // prologue: stage tiles 0 and 1 fully (16 loads/thread)
  STAGE_A(0, 0); STAGE_A(0, 1); STAGE_B(0, 0); STAGE_B(0, 1);
  STAGE_A(1, 0); STAGE_A(1, 1); STAGE_B(1, 0); STAGE_B(1, 1);
  asm volatile("s_waitcnt vmcnt(8)");          // tile 0 landed; tile 1 in flight
  __builtin_amdgcn_s_barrier();

  short8_t bfr[4][2];
  for (int S = 0; S < NT; ++S) {
    const int bs = (S & 1) * 16384;
#pragma unroll
    for (int p = 0; p < 4; ++p) {
      // ---- ds_read register subtiles ----
      short8_t afr[2][2];
#pragma unroll
      for (int mi = 0; mi < 2; ++mi)
#pragma unroll
        for (int kk = 0; kk < 2; ++kk) {
          const int r = (2 * p + mi) * 16 + q;
          afr[mi][kk] = *(const short8_t*)(Al + bs + ah * 8192 + r * 64 +
                                           ((kk * 4 + g) ^ (((r >> 2) & 1) << 1)) * 8);
        }
      if (p == 0) {
#pragma unroll
        for (int nf = 0; nf < 4; ++nf)
#pragma unroll
          for (int kk = 0; kk < 2; ++kk) {
            const int r = brow0 + nf * 16 + q;
            bfr[nf][kk] = *(const short8_t*)(Bl + bs + bh * 8192 + r * 64 +
                                             ((kk * 4 + g) ^ (((r >> 2) & 1) << 1)) * 8);
          }
      }
      // ---- issue one half-tile stage ----
      if (p == 0 && S >= 1 && S + 1 < NT) STAGE_A(S + 1, 0);
      if (p == 1 && S >= 1 && S + 1 < NT) STAGE_A(S + 1, 1);
      if (p == 2 && S + 2 < NT) STAGE_B(S + 2, 0);
      if (p == 3 && S + 2 < NT) STAGE_B(S + 2, 1);
      // ---- counted vmcnt once per K-tile, fencing tile S+1's reads ----
      if (p == 3) {
        if (S == NT - 2) { asm volatile("s_waitcnt vmcnt(0)"); }
        else if (S < NT - 2) { asm volatile("s_waitcnt vmcnt(4)"); }
      }
      __builtin_amdgcn_s_barrier();
      asm volatile("s_waitcnt lgkmcnt(0)" ::: "memory");
      __builtin_amdgcn_sched_barrier(0);
      __builtin_amdgcn_s_setprio(1);
#pragma unroll
      for (int nf = 0; nf < 4; ++nf)
#pragma unroll
        for (int mi = 0; mi < 2; ++mi)
#pragma unroll
          for (int kk = 0; kk < 2; ++kk)
            acc[2 * p + mi][nf] = __builtin_amdgcn_mfma_f32_16x16x32_bf16(
                afr[mi][kk], bfr[nf][kk], acc[2 * p + mi][nf], 0, 0, 0);
      __builtin_amdgcn_s_setprio(0);
      __builtin_amdgcn_s_barrier();
    }
  }
#undef STAGE_A
#undef STAGE_B

  // epilogue: bias + store (C/D: col=lane&15, row=(lane>>4)*4+j)
  const int wr = (w >> 2) * 128;
  const int s4 = wc >> 6;                         // t mod-4 class for MODE 2
#pragma unroll
  for (int nf = 0; nf < 4; ++nf) {
    const int col = n0 + wc + nf * 16 + q;        // linear modes
    const int dvt = nt * 64 + nf * 16 + q;        // MODE 2: d index
#pragma unroll
    for (int mf = 0; mf < 8; ++mf) {
      const int rowb = m0 + wr + mf * 16 + g * 4;
#pragma unroll
      for (int j = 0; j < 4; ++j) {
        const float vv = acc[mf][nf][j] + bv[nf];
        const int row = rowb + j;
        if (MODE == 0) {
          ((float*)Cout)[(size_t)row * N + col] = vv;
        } else if (MODE == 1) {
          ((u16*)Cout)[(size_t)row * N + col] = f2bf(vv);
        } else {
          // VT[hb][d][t]: hb=row>>8, d=dvt, t=(row&255)*4+s4 — block covers full
          // t-range and all mod-4 classes for 64 contiguous d-rows.
          ((u16*)Cout)[((size_t)(row >> 8) << 18) + ((size_t)dvt << 10) +
                       ((row & 255) * 4) + s4] = f2bf(vv);
        }
      }
    }
  }
#undef BROW
}

// -------- fused attention: R8 structure (KVBLK=32, T14 reg-staged) + T12 P-repack ----
// (unchanged from R10 — 142us plateau; five structural levers exhausted)
__global__ __launch_bounds__(256) void attn_kernel(const u16* __restrict__ Q,
                                                   const u16* __restrict__ Kf,
                                                   const u16* __restrict__ VT,
                                                   const float* __restrict__ adj,
                                                   u16* __restrict__ O) {
  __shared__ u16 Ks[32 * 256];    // K tile [key][d], 512B rows, slot ^= (row&7)
  __shared__ u16 Vs[256 * 32];    // V^T tile [d][key], 64B rows, sl ^= ((dr>>1)&3)
  const int tid = threadIdx.x, w = tid >> 6, l = tid & 63;
  const int g = l >> 4, q = l & 15;
  const int bid = blockIdx.x;
  const int xcd = bid & 7, idx = bid >> 3;           // 8 XCDs x 128 blocks
  const int b = xcd * 2 + (idx >> 6);                // 2 batches per XCD
  const int qb = (idx >> 2) & 15, h = idx & 3;       // qb sweeps, h fastest
  const int hb = h * 16 + b;
  const int q0 = qb * 64;
  const u16* qb_p = Q + ((size_t)hb * 1024 + q0 + w * 16) * 256;
  const u16* kb = Kf + (size_t)hb * 1024 * 256;
  const u16* vtb = VT + (size_t)hb * 256 * 1024;
  const float* adjr = adj + (size_t)b * 1024 * 1024 + (size_t)(q0 + w * 16 + q) * 1024;

  // per-thread staging geometry (constant across iterations)
  const int krow_b = tid >> 5;         // + i*8 -> K row 0..31
  const int kslot = tid & 31;          // 16B slot within 512B K row
  const int vdr_b = tid >> 2;          // + i*64 -> V^T d-row 0..255
  const int vsl = tid & 3;             // 16B slot within 64B V row

  // Q fragments (B-operand of S^T): lane q=l&15, d = kk*32 + g*8 + j
  short8_t qf[8];
#pragma unroll
  for (int kk = 0; kk < 8; ++kk)
    qf[kk] = *(const short8_t*)(qb_p + (size_t)q * 256 + kk * 32 + g * 8);

  f32x4 o[16];  // O^T accum: lane holds O[q][d], d = n*16 + g*4 + r
#pragma unroll
  for (int n = 0; n < 16; ++n) o[n] = fz4();
  float mrun = -1e30f, lrun = 0.f;

  short8_t kst[4], vst[4];   // reg-staged next tile (+32 VGPR)

#define LOADREGS(ktt)                                                              \
  {                                                                                \
    _Pragma("unroll") for (int i_ = 0; i_ < 4; ++i_) {                             \
      const int row_ = i_ * 8 + krow_b;                                            \
      kst[i_] = *(const short8_t*)(kb + (size_t)((ktt) * 32 + row_) * 256 +        \
                                   kslot * 8);                                     \
    }                                                                              \
    _Pragma("unroll") for (int i_ = 0; i_ < 4; ++i_) {                             \
      const int dr_ = i_ * 64 + vdr_b;                                             \
      vst[i_] = *(const short8_t*)(vtb + (size_t)dr_ * 1024 + (ktt) * 32 +         \
                                   vsl * 8);                                       \
    }                                                                              \
  }
#define WRITEREGS()                                                                \
  {                                                                                \
    _Pragma("unroll") for (int i_ = 0; i_ < 4; ++i_) {                             \
      const int row_ = i_ * 8 + krow_b;                                            \
      *(short8_t*)((char*)Ks + row_ * 512 + ((kslot ^ (row_ & 7)) * 16)) = kst[i_];\
    }                                                                              \
    _Pragma("unroll") for (int i_ = 0; i_ < 4; ++i_) {                             \
      const int dr_ = i_ * 64 + vdr_b;                                             \
      *(short8_t*)((char*)Vs + dr_ * 64 + ((vsl ^ ((dr_ >> 1) & 3)) * 16)) = vst[i_];\
    }                                                                              \
  }

  // prologue: tile 0 regs -> LDS; adj tile 0 prefetch
  LOADREGS(0);
  float4 a0 = *(const float4*)(adjr + 0 * 32 + 0 * 16 + g * 4);
  float4 a1 = *(const float4*)(adjr + 0 * 32 + 1 * 16 + g * 4);
  WRITEREGS();
  __syncthreads();

  for (int kt = 0; kt < 32; ++kt) {
    float4 n0v = a0, n1v = a1;
    if (kt < 31) {
      LOADREGS(kt + 1);            // issue early: latency hides under QK+sm+PV
      n0v = *(const float4*)(adjr + (kt + 1) * 32 + 0 * 16 + g * 4);
      n1v = *(const float4*)(adjr + (kt + 1) * 32 + 1 * 16 + g * 4);
    }

    // S^T = K Q^T : 2 key-frags x 8 d-steps. lane: q=l&15, k = f*16 + g*4 + r
    f32x4 s[2];
    __builtin_amdgcn_s_setprio(1);
#pragma unroll
    for (int f = 0; f < 2; ++f) {
      f32x4 a = fz4();
      const int row = f * 16 + q;
      const char* kr = (const char*)Ks + row * 512;
#pragma unroll
      for (int kk = 0; kk < 8; ++kk) {
        const int cb = kk * 64 + g * 16;
        short8_t kfr = *(const short8_t*)(kr + (cb ^ ((row & 7) << 4)));
        a = __builtin_amdgcn_mfma_f32_16x16x32_bf16(kfr, qf[kk], a, 0, 0, 0);
      }
      s[f] = a;
    }
    __builtin_amdgcn_s_setprio(0);

    // scale + adj (vectorized float4 per frag)
#pragma unroll
    for (int j = 0; j < 4; ++j) {
      s[0][j] = s[0][j] * 0.03125f + ((const float*)&a0)[j];
      s[1][j] = s[1][j] * 0.03125f + ((const float*)&a1)[j];
    }

    // per-lane online softmax: 8 local values + reduce across g (xor 16,32)
    float pmax = s[0][0];
#pragma unroll
    for (int j = 1; j < 4; ++j) pmax = fmaxf(pmax, s[0][j]);
#pragma unroll
    for (int j = 0; j < 4; ++j) pmax = fmaxf(pmax, s[1][j]);
    pmax = fmaxf(pmax, __shfl_xor(pmax, 16));
    pmax = fmaxf(pmax, __shfl_xor(pmax, 32));

    if (!__all(pmax - mrun <= 8.0f)) {          // T13 defer-max
      const float mn = fmaxf(mrun, pmax);
      const float al = __expf(mrun - mn);
      mrun = mn;
      lrun *= al;
#pragma unroll
      for (int n = 0; n < 16; ++n)
#pragma unroll
        for (int r = 0; r < 4; ++r) o[n][r] *= al;
    }

    float sum = 0.f;
#pragma unroll
    for (int f = 0; f < 2; ++f)
#pragma unroll
      for (int j = 0; j < 4; ++j) {
        const float p = __expf(s[f][j] - mrun);
        s[f][j] = p;
        sum += p;
      }
    sum += __shfl_xor(sum, 16);
    sum += __shfl_xor(sum, 32);
    lrun += sum;

    // ---- T12: P^T -> MFMA B-operand fully in-register ----
    uint32_t W00, W01, W10, W11;
    asm("v_cvt_pk_bf16_f32 %0, %1, %2" : "=v"(W00) : "v"(s[0][0]), "v"(s[0][1]));
    asm("v_cvt_pk_bf16_f32 %0, %1, %2" : "=v"(W01) : "v"(s[0][2]), "v"(s[0][3]));
    asm("v_cvt_pk_bf16_f32 %0, %1, %2" : "=v"(W10) : "v"(s[1][0]), "v"(s[1][1]));
    asm("v_cvt_pk_bf16_f32 %0, %1, %2" : "=v"(W11) : "v"(s[1][2]), "v"(s[1][3]));
    const uint32_t sA0 = (g < 2) ? W00 : W10;   // W[g>>1][0]
    const uint32_t sA1 = (g < 2) ? W01 : W11;   // W[g>>1][1]
    const uint32_t sB0 = (g < 2) ? W10 : W00;   // W[(g>>1)^1][0]
    const uint32_t sB1 = (g < 2) ? W11 : W01;   // W[(g>>1)^1][1]
    const uint32_t A0 = (uint32_t)__shfl_xor((int)sA0, 16);
    const uint32_t A1 = (uint32_t)__shfl_xor((int)sA1, 16);
    const uint32_t B0 = (uint32_t)__shfl_xor((int)sB0, 32);
    const uint32_t B1 = (uint32_t)__shfl_xor((int)sB1, 32);
    const uint32_t C0 = (uint32_t)__shfl_xor((int)sB0, 48);
    const uint32_t C1 = (uint32_t)__shfl_xor((int)sB1, 48);
    union { uint32_t u[4]; short8_t v; } pu;
    pu.u[0] = (g == 0) ? W00 : (g == 1) ? C0 : (g == 2) ? B0 : A0;
    pu.u[1] = (g == 0) ? W01 : (g == 1) ? C1 : (g == 2) ? B1 : A1;
    pu.u[2] = (g == 0) ? A0 : (g == 1) ? B0 : (g == 2) ? C0 : W10;
    pu.u[3] = (g == 0) ? A1 : (g == 1) ? B1 : (g == 2) ? C1 : W11;
    const short8_t pa = pu.v;

    // O^T += V^T P^T : 16 d-frags, one k-step (K=32 keys)
    __builtin_amdgcn_s_setprio(1);
#pragma unroll
    for (int n = 0; n < 16; ++n) {
      const int dr = n * 16 + q;
      const int sl = g ^ ((dr >> 1) & 3);
      short8_t vf = *(const short8_t*)((const char*)Vs + dr * 64 + sl * 16);
      o[n] = __builtin_amdgcn_mfma_f32_16x16x32_bf16(vf, pa, o[n], 0, 0, 0);
    }
    __builtin_amdgcn_s_setprio(0);

    if (kt < 31) {
      __syncthreads();             // all waves done reading Ks/Vs
      WRITEREGS();                 // compiler inserts vmcnt for reg deps
      __syncthreads();             // writes visible
    }
    a0 = n0v; a1 = n1v;
  }
#undef LOADREGS
#undef WRITEREGS

  // epilogue: normalize, packed 8B stores; lane owns row q, d = n*16+g*4+r
  const float inv = 1.0f / lrun;
  u16* ob = O + ((size_t)hb * 1024 + q0 + w * 16 + q) * 256;
#pragma unroll
  for (int n = 0; n < 16; ++n) {
    ushort4 st;
    st.x = f2bf(o[n][0] * inv); st.y = f2bf(o[n][1] * inv);
    st.z = f2bf(o[n][2] * inv); st.w = f2bf(o[n][3] * inv);
    *(ushort4*)(ob + n * 16 + g * 4) = st;
  }
}

extern "C" void kernel_launch(void* const* d_in, const int* in_sizes, int n_in,
                              void* d_out, int out_size, void* d_ws, size_t ws_size,
                              hipStream_t stream) {
  (void)in_sizes; (void)n_in; (void)out_size; (void)ws_size;
  const float* x   = (const float*)d_in[0];
  const float* y   = (const float*)d_in[1];
  const float* adj = (const float*)d_in[2];
  const float* Wq  = (const float*)d_in[3];
  const float* bq  = (const float*)d_in[4];
  const float* Wk  = (const float*)d_in[5];
  const float* bk  = (const float*)d_in[6];
  const float* Wv  = (const float*)d_in[7];
  const float* bv  = (const float*)d_in[8];
  const float* Wo  = (const float*)d_in[9];
  const float* bo  = (const float*)d_in[10];

  char* ws = (char*)d_ws;
  const size_t MB = 1ull << 20;
  u16* Xb  = (u16*)(ws + 0);        // 32MB, reused as Tmp after Q GEMM
  u16* Yb  = (u16*)(ws + 32 * MB);  // 32MB
  u16* Wqb = (u16*)(ws + 64 * MB);  // 2MB each
  u16* Wkb = (u16*)(ws + 66 * MB);
  u16* Wvb = (u16*)(ws + 68 * MB);
  u16* Wob = (u16*)(ws + 70 * MB);
  u16* Qb  = (u16*)(ws + 72 * MB);  // 32MB
  u16* Kb  = (u16*)(ws + 104 * MB);
  u16* VTb = (u16*)(ws + 168 * MB); // V GEMM writes transposed layout directly
  u16* Tmp = Xb;

  cast2_kernel<<<32768, 256, 0, stream>>>(x, y, Xb, Yb);
  cast4_kernel<<<4096, 256, 0, stream>>>(Wq, Wk, Wv, Wo, Wqb, Wkb, Wvb, Wob);

  gemm8<1><<<256, 512, 0, stream>>>(Xb, Wqb, bq, Qb, 16384, 1024, 1024);
  gemm8<1><<<256, 512, 0, stream>>>(Yb, Wkb, bk, Kb, 16384, 1024, 1024);
  gemm8<2><<<256, 512, 0, stream>>>(Yb, Wvb, bv, VTb, 16384, 1024, 1024);

  attn_kernel<<<1024, 256, 0, stream>>>(Qb, Kb, VTb, adj, Tmp);

  gemm8<0><<<256, 512, 0, stream>>>(Tmp, Wob, bo, d_out, 16384, 1024, 1024);
}

// Round 14
// 332.261 us; speedup vs baseline: 1.1438x; 1.0836x over previous
//
#include <hip/hip_runtime.h>
#include <stdint.h>
#include <string.h>

typedef unsigned short u16;
typedef __attribute__((ext_vector_type(8))) short short8_t;   // 8 x bf16 (4 VGPRs)
typedef __attribute__((ext_vector_type(4))) float f32x4;

typedef const __attribute__((address_space(1))) void GV;
typedef __attribute__((address_space(3))) void LV;

__device__ __forceinline__ void gload_lds16(const void* g, void* l) {
  // async global->LDS, 16B per lane; LDS dest is wave-uniform base + lane*16
  __builtin_amdgcn_global_load_lds((GV*)g, (LV*)l, 16, 0, 0);
}

__device__ __forceinline__ u16 f2bf(float f) {
  union { float f; uint32_t u; } v; v.f = f;
  return (u16)((v.u + 0x7FFFu + ((v.u >> 16) & 1u)) >> 16);  // RNE
}

__device__ __forceinline__ f32x4 fz4() { f32x4 v = {0.f, 0.f, 0.f, 0.f}; return v; }

// ------------- all casts fp32 -> bf16 (4 elems/thread) in ONE launch -------------
__global__ __launch_bounds__(256) void cast_all(const float* __restrict__ x,
                                                const float* __restrict__ y,
                                                const float* __restrict__ w0,
                                                const float* __restrict__ w1,
                                                const float* __restrict__ w2,
                                                const float* __restrict__ w3,
                                                u16* __restrict__ xo,
                                                u16* __restrict__ yo,
                                                u16* __restrict__ o0,
                                                u16* __restrict__ o1,
                                                u16* __restrict__ o2,
                                                u16* __restrict__ o3) {
  const int bid = blockIdx.x;
  const float* in;
  u16* out;
  int off;
  if (bid < 32768) {
    in = (bid < 16384) ? x : y;
    out = (bid < 16384) ? xo : yo;
    off = bid & 16383;
  } else {
    const int s = (bid - 32768) >> 10;
    in = s == 0 ? w0 : s == 1 ? w1 : s == 2 ? w2 : w3;
    out = s == 0 ? o0 : s == 1 ? o1 : s == 2 ? o2 : o3;
    off = (bid - 32768) & 1023;
  }
  int i = (off * 256 + threadIdx.x) * 4;
  float4 v = *(const float4*)(in + i);
  ushort4 o;
  o.x = f2bf(v.x); o.y = f2bf(v.y); o.z = f2bf(v.z); o.w = f2bf(v.w);
  *(ushort4*)(out + i) = o;
}

// ======== 256x256 8-phase GEMM core (T2+T3+T4+T5): C = A[M,K]*B[N,K]^T + bias ========
// Schedule unchanged from R6. R11 T1 mapping: xcd=bid&7, n fastest, contiguous
// 8-m-tile range per XCD. Per-mode COLUMN PERMUTATION makes all epilogue stores
// vectorized (R13 lesson: scalar 2B scatter cost ~19us on the V GEMM):
//  MODE 0/1 (linear f32/bf16): phys(u) = n0 + (u&0xC0) + (u&15)*4 + ((u>>4)&3)
//    -> thread's 4 nf-values = 4 consecutive cols at wc+q*4 -> float4/ushort4 store.
//  MODE 2 (bf16 -> VT[hb][d][t]): phys(u) = ((u>>4)&3)*256 + nt*64 + ((u>>6)&3)*16 + (u&15)
//    -> c>>8 = nf (per-thread) so nf-quad = t-quad (row&255)*4..+3 at d = nt*64+(w&3)*16+q
//    -> one ushort4 VT store per (mf,j). Permutation applied to B-staging source + bias.
template <int MODE>
__device__ __forceinline__ void gemm8_core(int bid, const u16* __restrict__ A,
                                           const u16* __restrict__ B,
                                           const float* __restrict__ bias,
                                           void* __restrict__ Cout,
                                           u16* Al, u16* Bl) {
  const int N = 1024, K = 1024;
  const int tid = threadIdx.x, w = tid >> 6, l = tid & 63;
  const int g = l >> 4, q = l & 15;
  const int xcd = bid & 7;
  const int nt = (bid >> 3) & 3;                 // n fastest within XCD
  const int mt = xcd * 8 + (bid >> 5);           // contiguous m-range per XCD
  const int n0 = nt * 256, m0 = mt * 256;
  const int NT = K >> 6;
  const int ah = w >> 2;            // this wave's A half
  const int bh = (w & 3) >> 1;      // this wave's B half
  const int brow0 = ((w & 3) & 1) * 64;

  // logical B row u (0..255) -> physical B row (column of C)
#define BROW(u)                                                                   \
  (MODE == 2 ? ((((u) >> 4) & 3) * 256 + nt * 64 + (((u) >> 6) & 3) * 16 + ((u) & 15)) \
             : (n0 + (((u) & 0xC0) | (((u) & 15) << 2) | (((u) >> 4) & 3))))

#define STAGE_A(S, half)                                                          \
  {                                                                               \
    _Pragma("unroll") for (int j_ = 0; j_ < 2; ++j_) {                            \
      const int idx_ = j_ * 512 + tid;                                            \
      const int row_ = idx_ >> 3;                                                 \
      const int sl_ = (idx_ & 7) ^ (((idx_ >> 5) & 1) << 1);                      \
      gload_lds16(A + (size_t)(m0 + (half) * 128 + row_) * K + (S) * 64 + sl_ * 8,\
                  Al + ((S) & 1) * 16384 + (half) * 8192 + (j_ * 512 + w * 64) * 8);\
    }                                                                             \
  }
#define STAGE_B(S, half)                                                          \
  {                                                                               \
    _Pragma("unroll") for (int j_ = 0; j_ < 2; ++j_) {                            \
      const int idx_ = j_ * 512 + tid;                                            \
      const int row_ = idx_ >> 3;                                                 \
      const int sl_ = (idx_ & 7) ^ (((idx_ >> 5) & 1) << 1);                      \
      const int pr_ = BROW((half) * 128 + row_);                                  \
      gload_lds16(B + (size_t)pr_ * K + (S) * 64 + sl_ * 8,                       \
                  Bl + ((S) & 1) * 16384 + (half) * 8192 + (j_ * 512 + w * 64) * 8);\
    }                                                                             \
  }

  f32x4 acc[8][4];
#pragma unroll
  for (int i = 0; i < 8; ++i)
#pragma unroll
    for (int n = 0; n < 4; ++n) acc[i][n] = fz4();

  // bias per lane (epilogue operand), load early; index = physical column
  const int wc = (w & 3) * 64;
  float bv[4];
#pragma unroll
  for (int nf = 0; nf < 4; ++nf) bv[nf] = bias[BROW(wc + nf * 16 + q)];

  // prologue: stage tiles 0 and 1 fully (16 loads/thread)
  STAGE_A(0, 0); STAGE_A(0, 1); STAGE_B(0, 0); STAGE_B(0, 1);
  STAGE_A(1, 0); STAGE_A(1, 1); STAGE_B(1, 0); STAGE_B(1, 1);
  asm volatile("s_waitcnt vmcnt(8)");          // tile 0 landed; tile 1 in flight
  __builtin_amdgcn_s_barrier();

  short8_t bfr[4][2];
  for (int S = 0; S < NT; ++S) {
    const int bs = (S & 1) * 16384;
#pragma unroll
    for (int p = 0; p < 4; ++p) {
      // ---- ds_read register subtiles ----
      short8_t afr[2][2];
#pragma unroll
      for (int mi = 0; mi < 2; ++mi)
#pragma unroll
        for (int kk = 0; kk < 2; ++kk) {
          const int r = (2 * p + mi) * 16 + q;
          afr[mi][kk] = *(const short8_t*)(Al + bs + ah * 8192 + r * 64 +
                                           ((kk * 4 + g) ^ (((r >> 2) & 1) << 1)) * 8);
        }
      if (p == 0) {
#pragma unroll
        for (int nf = 0; nf < 4; ++nf)
#pragma unroll
          for (int kk = 0; kk < 2; ++kk) {
            const int r = brow0 + nf * 16 + q;
            bfr[nf][kk] = *(const short8_t*)(Bl + bs + bh * 8192 + r * 64 +
                                             ((kk * 4 + g) ^ (((r >> 2) & 1) << 1)) * 8);
          }
      }
      // ---- issue one half-tile stage ----
      if (p == 0 && S >= 1 && S + 1 < NT) STAGE_A(S + 1, 0);
      if (p == 1 && S >= 1 && S + 1 < NT) STAGE_A(S + 1, 1);
      if (p == 2 && S + 2 < NT) STAGE_B(S + 2, 0);
      if (p == 3 && S + 2 < NT) STAGE_B(S + 2, 1);
      // ---- counted vmcnt once per K-tile, fencing tile S+1's reads ----
      if (p == 3) {
        if (S == NT - 2) { asm volatile("s_waitcnt vmcnt(0)"); }
        else if (S < NT - 2) { asm volatile("s_waitcnt vmcnt(4)"); }
      }
      __builtin_amdgcn_s_barrier();
      asm volatile("s_waitcnt lgkmcnt(0)" ::: "memory");
      __builtin_amdgcn_sched_barrier(0);
      __builtin_amdgcn_s_setprio(1);
#pragma unroll
      for (int nf = 0; nf < 4; ++nf)
#pragma unroll
        for (int mi = 0; mi < 2; ++mi)
#pragma unroll
          for (int kk = 0; kk < 2; ++kk)
            acc[2 * p + mi][nf] = __builtin_amdgcn_mfma_f32_16x16x32_bf16(
                afr[mi][kk], bfr[nf][kk], acc[2 * p + mi][nf], 0, 0, 0);
      __builtin_amdgcn_s_setprio(0);
      __builtin_amdgcn_s_barrier();
    }
  }
#undef STAGE_A
#undef STAGE_B
#undef BROW

  // epilogue: bias + VECTOR stores (C/D: col=lane&15, row=(lane>>4)*4+j)
  const int wr = (w >> 2) * 128;
  if (MODE == 2) {
    const int dvt = nt * 64 + (w & 3) * 16 + q;   // d index (c&255)
#pragma unroll
    for (int mf = 0; mf < 8; ++mf) {
#pragma unroll
      for (int j = 0; j < 4; ++j) {
        const int row = m0 + wr + mf * 16 + g * 4 + j;
        ushort4 st;
        st.x = f2bf(acc[mf][0][j] + bv[0]);
        st.y = f2bf(acc[mf][1][j] + bv[1]);
        st.z = f2bf(acc[mf][2][j] + bv[2]);
        st.w = f2bf(acc[mf][3][j] + bv[3]);
        *(ushort4*)((u16*)Cout + (((size_t)(row >> 8)) << 18) +
                    (((size_t)dvt) << 10) + ((row & 255) << 2)) = st;
      }
    }
  } else {
    const int colb = n0 + wc + q * 4;             // 4 consecutive physical cols
#pragma unroll
    for (int mf = 0; mf < 8; ++mf) {
#pragma unroll
      for (int j = 0; j < 4; ++j) {
        const int row = m0 + wr + mf * 16 + g * 4 + j;
        if (MODE == 0) {
          float4 fv;
          fv.x = acc[mf][0][j] + bv[0];
          fv.y = acc[mf][1][j] + bv[1];
          fv.z = acc[mf][2][j] + bv[2];
          fv.w = acc[mf][3][j] + bv[3];
          *(float4*)((float*)Cout + (size_t)row * N + colb) = fv;
        } else {
          ushort4 st;
          st.x = f2bf(acc[mf][0][j] + bv[0]);
          st.y = f2bf(acc[mf][1][j] + bv[1]);
          st.z = f2bf(acc[mf][2][j] + bv[2]);
          st.w = f2bf(acc[mf][3][j] + bv[3]);
          *(ushort4*)((u16*)Cout + (size_t)row * N + colb) = st;
        }
      }
    }
  }
}

// Merged Q/K/V GEMMs: 768 blocks, 256 per GEMM (merge itself proven neutral in R12;
// its regression was the store bug, now fixed by the MODE-2 permutation).
__global__ __launch_bounds__(512, 2) void gemm8_qkv(const u16* __restrict__ Xb,
                                                    const u16* __restrict__ Yb,
                                                    const u16* __restrict__ Wqb,
                                                    const u16* __restrict__ Wkb,
                                                    const u16* __restrict__ Wvb,
                                                    const float* __restrict__ bq,
                                                    const float* __restrict__ bk,
                                                    const float* __restrict__ bv,
                                                    u16* __restrict__ Qb,
                                                    u16* __restrict__ Kb,
                                                    u16* __restrict__ VTb) {
  __shared__ u16 Al[2 * 16384];
  __shared__ u16 Bl[2 * 16384];
  const int sel = blockIdx.x >> 8, bid = blockIdx.x & 255;
  if (sel == 0)      gemm8_core<1>(bid, Xb, Wqb, bq, Qb, Al, Bl);
  else if (sel == 1) gemm8_core<1>(bid, Yb, Wkb, bk, Kb, Al, Bl);
  else               gemm8_core<2>(bid, Yb, Wvb, bv, VTb, Al, Bl);
}

__global__ __launch_bounds__(512, 2) void gemm8_out(const u16* __restrict__ A,
                                                    const u16* __restrict__ B,
                                                    const float* __restrict__ bias,
                                                    float* __restrict__ C) {
  __shared__ u16 Al[2 * 16384];
  __shared__ u16 Bl[2 * 16384];
  gemm8_core<0>(blockIdx.x, A, B, bias, C, Al, Bl);
}

// -------- fused attention: R8 structure (KVBLK=32, T14 reg-staged) + T12 P-repack ----
// (unchanged from R10 — 142us plateau; five structural levers exhausted)
__global__ __launch_bounds__(256) void attn_kernel(const u16* __restrict__ Q,
                                                   const u16* __restrict__ Kf,
                                                   const u16* __restrict__ VT,
                                                   const float* __restrict__ adj,
                                                   u16* __restrict__ O) {
  __shared__ u16 Ks[32 * 256];    // K tile [key][d], 512B rows, slot ^= (row&7)
  __shared__ u16 Vs[256 * 32];    // V^T tile [d][key], 64B rows, sl ^= ((dr>>1)&3)
  const int tid = threadIdx.x, w = tid >> 6, l = tid & 63;
  const int g = l >> 4, q = l & 15;
  const int bid = blockIdx.x;
  const int xcd = bid & 7, idx = bid >> 3;           // 8 XCDs x 128 blocks
  const int b = xcd * 2 + (idx >> 6);                // 2 batches per XCD
  const int qb = (idx >> 2) & 15, h = idx & 3;       // qb sweeps, h fastest
  const int hb = h * 16 + b;
  const int q0 = qb * 64;
  const u16* qb_p = Q + ((size_t)hb * 1024 + q0 + w * 16) * 256;
  const u16* kb = Kf + (size_t)hb * 1024 * 256;
  const u16* vtb = VT + (size_t)hb * 256 * 1024;
  const float* adjr = adj + (size_t)b * 1024 * 1024 + (size_t)(q0 + w * 16 + q) * 1024;

  // per-thread staging geometry (constant across iterations)
  const int krow_b = tid >> 5;         // + i*8 -> K row 0..31
  const int kslot = tid & 31;          // 16B slot within 512B K row
  const int vdr_b = tid >> 2;          // + i*64 -> V^T d-row 0..255
  const int vsl = tid & 3;             // 16B slot within 64B V row

  // Q fragments (B-operand of S^T): lane q=l&15, d = kk*32 + g*8 + j
  short8_t qf[8];
#pragma unroll
  for (int kk = 0; kk < 8; ++kk)
    qf[kk] = *(const short8_t*)(qb_p + (size_t)q * 256 + kk * 32 + g * 8);

  f32x4 o[16];  // O^T accum: lane holds O[q][d], d = n*16 + g*4 + r
#pragma unroll
  for (int n = 0; n < 16; ++n) o[n] = fz4();
  float mrun = -1e30f, lrun = 0.f;

  short8_t kst[4], vst[4];   // reg-staged next tile (+32 VGPR)

#define LOADREGS(ktt)                                                              \
  {                                                                                \
    _Pragma("unroll") for (int i_ = 0; i_ < 4; ++i_) {                             \
      const int row_ = i_ * 8 + krow_b;                                            \
      kst[i_] = *(const short8_t*)(kb + (size_t)((ktt) * 32 + row_) * 256 +        \
                                   kslot * 8);                                     \
    }                                                                              \
    _Pragma("unroll") for (int i_ = 0; i_ < 4; ++i_) {                             \
      const int dr_ = i_ * 64 + vdr_b;                                             \
      vst[i_] = *(const short8_t*)(vtb + (size_t)dr_ * 1024 + (ktt) * 32 +         \
                                   vsl * 8);                                       \
    }                                                                              \
  }
#define WRITEREGS()                                                                \
  {                                                                                \
    _Pragma("unroll") for (int i_ = 0; i_ < 4; ++i_) {                             \
      const int row_ = i_ * 8 + krow_b;                                            \
      *(short8_t*)((char*)Ks + row_ * 512 + ((kslot ^ (row_ & 7)) * 16)) = kst[i_];\
    }                                                                              \
    _Pragma("unroll") for (int i_ = 0; i_ < 4; ++i_) {                             \
      const int dr_ = i_ * 64 + vdr_b;                                             \
      *(short8_t*)((char*)Vs + dr_ * 64 + ((vsl ^ ((dr_ >> 1) & 3)) * 16)) = vst[i_];\
    }                                                                              \
  }

  // prologue: tile 0 regs -> LDS; adj tile 0 prefetch
  LOADREGS(0);
  float4 a0 = *(const float4*)(adjr + 0 * 32 + 0 * 16 + g * 4);
  float4 a1 = *(const float4*)(adjr + 0 * 32 + 1 * 16 + g * 4);
  WRITEREGS();
  __syncthreads();

  for (int kt = 0; kt < 32; ++kt) {
    float4 n0v = a0, n1v = a1;
    if (kt < 31) {
      LOADREGS(kt + 1);            // issue early: latency hides under QK+sm+PV
      n0v = *(const float4*)(adjr + (kt + 1) * 32 + 0 * 16 + g * 4);
      n1v = *(const float4*)(adjr + (kt + 1) * 32 + 1 * 16 + g * 4);
    }

    // S^T = K Q^T : 2 key-frags x 8 d-steps. lane: q=l&15, k = f*16 + g*4 + r
    f32x4 s[2];
    __builtin_amdgcn_s_setprio(1);
#pragma unroll
    for (int f = 0; f < 2; ++f) {
      f32x4 a = fz4();
      const int row = f * 16 + q;
      const char* kr = (const char*)Ks + row * 512;
#pragma unroll
      for (int kk = 0; kk < 8; ++kk) {
        const int cb = kk * 64 + g * 16;
        short8_t kfr = *(const short8_t*)(kr + (cb ^ ((row & 7) << 4)));
        a = __builtin_amdgcn_mfma_f32_16x16x32_bf16(kfr, qf[kk], a, 0, 0, 0);
      }
      s[f] = a;
    }
    __builtin_amdgcn_s_setprio(0);

    // scale + adj (vectorized float4 per frag)
#pragma unroll
    for (int j = 0; j < 4; ++j) {
      s[0][j] = s[0][j] * 0.03125f + ((const float*)&a0)[j];
      s[1][j] = s[1][j] * 0.03125f + ((const float*)&a1)[j];
    }

    // per-lane online softmax: 8 local values + reduce across g (xor 16,32)
    float pmax = s[0][0];
#pragma unroll
    for (int j = 1; j < 4; ++j) pmax = fmaxf(pmax, s[0][j]);
#pragma unroll
    for (int j = 0; j < 4; ++j) pmax = fmaxf(pmax, s[1][j]);
    pmax = fmaxf(pmax, __shfl_xor(pmax, 16));
    pmax = fmaxf(pmax, __shfl_xor(pmax, 32));

    if (!__all(pmax - mrun <= 8.0f)) {          // T13 defer-max
      const float mn = fmaxf(mrun, pmax);
      const float al = __expf(mrun - mn);
      mrun = mn;
      lrun *= al;
#pragma unroll
      for (int n = 0; n < 16; ++n)
#pragma unroll
        for (int r = 0; r < 4; ++r) o[n][r] *= al;
    }

    float sum = 0.f;
#pragma unroll
    for (int f = 0; f < 2; ++f)
#pragma unroll
      for (int j = 0; j < 4; ++j) {
        const float p = __expf(s[f][j] - mrun);
        s[f][j] = p;
        sum += p;
      }
    sum += __shfl_xor(sum, 16);
    sum += __shfl_xor(sum, 32);
    lrun += sum;

    // ---- T12: P^T -> MFMA B-operand fully in-register ----
    uint32_t W00, W01, W10, W11;
    asm("v_cvt_pk_bf16_f32 %0, %1, %2" : "=v"(W00) : "v"(s[0][0]), "v"(s[0][1]));
    asm("v_cvt_pk_bf16_f32 %0, %1, %2" : "=v"(W01) : "v"(s[0][2]), "v"(s[0][3]));
    asm("v_cvt_pk_bf16_f32 %0, %1, %2" : "=v"(W10) : "v"(s[1][0]), "v"(s[1][1]));
    asm("v_cvt_pk_bf16_f32 %0, %1, %2" : "=v"(W11) : "v"(s[1][2]), "v"(s[1][3]));
    const uint32_t sA0 = (g < 2) ? W00 : W10;   // W[g>>1][0]
    const uint32_t sA1 = (g < 2) ? W01 : W11;   // W[g>>1][1]
    const uint32_t sB0 = (g < 2) ? W10 : W00;   // W[(g>>1)^1][0]
    const uint32_t sB1 = (g < 2) ? W11 : W01;   // W[(g>>1)^1][1]
    const uint32_t A0 = (uint32_t)__shfl_xor((int)sA0, 16);
    const uint32_t A1 = (uint32_t)__shfl_xor((int)sA1, 16);
    const uint32_t B0 = (uint32_t)__shfl_xor((int)sB0, 32);
    const uint32_t B1 = (uint32_t)__shfl_xor((int)sB1, 32);
    const uint32_t C0 = (uint32_t)__shfl_xor((int)sB0, 48);
    const uint32_t C1 = (uint32_t)__shfl_xor((int)sB1, 48);
    union { uint32_t u[4]; short8_t v; } pu;
    pu.u[0] = (g == 0) ? W00 : (g == 1) ? C0 : (g == 2) ? B0 : A0;
    pu.u[1] = (g == 0) ? W01 : (g == 1) ? C1 : (g == 2) ? B1 : A1;
    pu.u[2] = (g == 0) ? A0 : (g == 1) ? B0 : (g == 2) ? C0 : W10;
    pu.u[3] = (g == 0) ? A1 : (g == 1) ? B1 : (g == 2) ? C1 : W11;
    const short8_t pa = pu.v;

    // O^T += V^T P^T : 16 d-frags, one k-step (K=32 keys)
    __builtin_amdgcn_s_setprio(1);
#pragma unroll
    for (int n = 0; n < 16; ++n) {
      const int dr = n * 16 + q;
      const int sl = g ^ ((dr >> 1) & 3);
      short8_t vf = *(const short8_t*)((const char*)Vs + dr * 64 + sl * 16);
      o[n] = __builtin_amdgcn_mfma_f32_16x16x32_bf16(vf, pa, o[n], 0, 0, 0);
    }
    __builtin_amdgcn_s_setprio(0);

    if (kt < 31) {
      __syncthreads();             // all waves done reading Ks/Vs
      WRITEREGS();                 // compiler inserts vmcnt for reg deps
      __syncthreads();             // writes visible
    }
    a0 = n0v; a1 = n1v;
  }
#undef LOADREGS
#undef WRITEREGS

  // epilogue: normalize, packed 8B stores; lane owns row q, d = n*16+g*4+r
  const float inv = 1.0f / lrun;
  u16* ob = O + ((size_t)hb * 1024 + q0 + w * 16 + q) * 256;
#pragma unroll
  for (int n = 0; n < 16; ++n) {
    ushort4 st;
    st.x = f2bf(o[n][0] * inv); st.y = f2bf(o[n][1] * inv);
    st.z = f2bf(o[n][2] * inv); st.w = f2bf(o[n][3] * inv);
    *(ushort4*)(ob + n * 16 + g * 4) = st;
  }
}

extern "C" void kernel_launch(void* const* d_in, const int* in_sizes, int n_in,
                              void* d_out, int out_size, void* d_ws, size_t ws_size,
                              hipStream_t stream) {
  (void)in_sizes; (void)n_in; (void)out_size; (void)ws_size;
  const float* x   = (const float*)d_in[0];
  const float* y   = (const float*)d_in[1];
  const float* adj = (const float*)d_in[2];
  const float* Wq  = (const float*)d_in[3];
  const float* bq  = (const float*)d_in[4];
  const float* Wk  = (const float*)d_in[5];
  const float* bk  = (const float*)d_in[6];
  const float* Wv  = (const float*)d_in[7];
  const float* bv  = (const float*)d_in[8];
  const float* Wo  = (const float*)d_in[9];
  const float* bo  = (const float*)d_in[10];

  char* ws = (char*)d_ws;
  const size_t MB = 1ull << 20;
  u16* Xb  = (u16*)(ws + 0);        // 32MB, reused as Tmp after Q GEMM
  u16* Yb  = (u16*)(ws + 32 * MB);  // 32MB
  u16* Wqb = (u16*)(ws + 64 * MB);  // 2MB each
  u16* Wkb = (u16*)(ws + 66 * MB);
  u16* Wvb = (u16*)(ws + 68 * MB);
  u16* Wob = (u16*)(ws + 70 * MB);
  u16* Qb  = (u16*)(ws + 72 * MB);  // 32MB
  u16* Kb  = (u16*)(ws + 104 * MB);
  u16* VTb = (u16*)(ws + 168 * MB); // V GEMM writes transposed layout directly
  u16* Tmp = Xb;

  cast_all<<<36864, 256, 0, stream>>>(x, y, Wq, Wk, Wv, Wo,
                                      Xb, Yb, Wqb, Wkb, Wvb, Wob);

  gemm8_qkv<<<768, 512, 0, stream>>>(Xb, Yb, Wqb, Wkb, Wvb, bq, bk, bv, Qb, Kb, VTb);

  attn_kernel<<<1024, 256, 0, stream>>>(Qb, Kb, VTb, adj, Tmp);

  gemm8_out<<<256, 512, 0, stream>>>(Tmp, Wob, bo, (float*)d_out);
}